// Round 1
// baseline (365.971 us; speedup 1.0000x reference)
//
#include <hip/hip_runtime.h>

#define N_NODES 40000
#define N_EDGES 640000
#define IN_F 128
#define HID_F 256
#define CLS_F 40
#define MB 16   // nodes per block in fused MLP

// ---------------- CSR build ----------------

__global__ void k_count(const int* __restrict__ dst, int* __restrict__ counts) {
    int e = blockIdx.x * blockDim.x + threadIdx.x;
    if (e < N_EDGES) atomicAdd(&counts[dst[e]], 1);
}

__global__ void k_scan1(const int* __restrict__ counts, int* __restrict__ bsum) {
    __shared__ int s[256];
    int i = blockIdx.x * 256 + threadIdx.x;
    s[threadIdx.x] = (i < N_NODES) ? counts[i] : 0;
    __syncthreads();
    for (int off = 128; off > 0; off >>= 1) {
        if (threadIdx.x < off) s[threadIdx.x] += s[threadIdx.x + off];
        __syncthreads();
    }
    if (threadIdx.x == 0) bsum[blockIdx.x] = s[0];
}

__global__ void k_scan2(int* __restrict__ bsum, int nb) {
    if (blockIdx.x == 0 && threadIdx.x == 0) {
        int run = 0;
        for (int b = 0; b < nb; b++) { int t = bsum[b]; bsum[b] = run; run += t; }
    }
}

__global__ void k_scan3(const int* __restrict__ counts, const int* __restrict__ bsum,
                        int* __restrict__ rowptr, int* __restrict__ cursor) {
    __shared__ int s[256];
    int t = threadIdx.x;
    int i = blockIdx.x * 256 + t;
    int v = (i < N_NODES) ? counts[i] : 0;
    s[t] = v;
    __syncthreads();
    for (int off = 1; off < 256; off <<= 1) {
        int x = (t >= off) ? s[t - off] : 0;
        __syncthreads();
        s[t] += x;
        __syncthreads();
    }
    if (i < N_NODES) {
        int excl = s[t] - v + bsum[blockIdx.x];
        rowptr[i] = excl;
        cursor[i] = excl;
    }
}

__global__ void k_norm(const int* __restrict__ counts,
                       float* __restrict__ norm, float* __restrict__ norm2) {
    int i = blockIdx.x * blockDim.x + threadIdx.x;
    if (i < N_NODES) {
        float d = (float)counts[i];
        float r = rsqrtf(fmaxf(d, 1.0f));
        norm[i] = r;
        norm2[i] = r * r;
    }
}

__global__ void k_fill(const int* __restrict__ src, const int* __restrict__ dst,
                       int* __restrict__ cursor, int* __restrict__ csr_src) {
    int e = blockIdx.x * blockDim.x + threadIdx.x;
    if (e < N_EDGES) {
        int d = dst[e];
        int p = atomicAdd(&cursor[d], 1);
        csr_src[p] = src[e];
    }
}

// ---------------- propagation hop (gather, no atomics) ----------------
// out[n][:] = sum_{e in in-edges(n)} in[src(e)][:] * scale[src(e)]
// 32 lanes per node, float4 per lane -> one coalesced 512B row read per edge.

__global__ __launch_bounds__(256) void k_hop(
        const float* __restrict__ gin, float* __restrict__ gout,
        const int* __restrict__ csr_src, const int* __restrict__ rowptr,
        const int* __restrict__ counts, const float* __restrict__ scale) {
    int gid  = blockIdx.x * 8 + (threadIdx.x >> 5);
    int lane = threadIdx.x & 31;
    if (gid >= N_NODES) return;
    int start = rowptr[gid];
    int cnt   = counts[gid];
    float4 acc = make_float4(0.f, 0.f, 0.f, 0.f);
    for (int i = 0; i < cnt; i++) {
        int s = csr_src[start + i];
        float sc = scale[s];
        float4 v = ((const float4*)(gin + (size_t)s * IN_F))[lane];
        acc.x = fmaf(v.x, sc, acc.x);
        acc.y = fmaf(v.y, sc, acc.y);
        acc.z = fmaf(v.z, sc, acc.z);
        acc.w = fmaf(v.w, sc, acc.w);
    }
    ((float4*)(gout + (size_t)gid * IN_F))[lane] = acc;
}

// ---------------- fused MLP: (h2*norm) @ W1 + b1 -> relu -> @ W2 + b2 ----------------

__global__ __launch_bounds__(256) void k_mlp(
        const float* __restrict__ h2, const float* __restrict__ norm,
        const float* __restrict__ W1, const float* __restrict__ b1,
        const float* __restrict__ W2, const float* __restrict__ b2,
        float* __restrict__ out) {
    __shared__ __align__(16) float hs[MB * IN_F];   // 8 KB
    __shared__ float ts[MB * HID_F];                // 16 KB
    int n0 = blockIdx.x * MB;
    int t  = threadIdx.x;

    // load 16 node rows, folding the trailing norm[dst] of hop 2
    for (int idx = t; idx < MB * IN_F; idx += 256) {
        int m = idx >> 7;
        hs[idx] = h2[(size_t)(n0 + m) * IN_F + (idx & 127)] * norm[n0 + m];
    }
    __syncthreads();

    // GEMM1: thread t owns hidden column t
    float acc[MB];
    #pragma unroll
    for (int m = 0; m < MB; m++) acc[m] = 0.f;
    const float4* hs4 = (const float4*)hs;
    for (int k4 = 0; k4 < IN_F / 4; k4++) {
        float w0 = W1[(k4 * 4 + 0) * HID_F + t];
        float w1 = W1[(k4 * 4 + 1) * HID_F + t];
        float w2 = W1[(k4 * 4 + 2) * HID_F + t];
        float w3 = W1[(k4 * 4 + 3) * HID_F + t];
        #pragma unroll
        for (int m = 0; m < MB; m++) {
            float4 h4 = hs4[m * (IN_F / 4) + k4];   // LDS broadcast, ds_read_b128
            acc[m] = fmaf(h4.x, w0, acc[m]);
            acc[m] = fmaf(h4.y, w1, acc[m]);
            acc[m] = fmaf(h4.z, w2, acc[m]);
            acc[m] = fmaf(h4.w, w3, acc[m]);
        }
    }
    float bb = b1[t];
    #pragma unroll
    for (int m = 0; m < MB; m++) {
        float v = acc[m] + bb;
        ts[m * HID_F + t] = v > 0.f ? v : 0.f;
    }
    __syncthreads();

    // GEMM2: 16x40 = 640 outputs over 256 threads
    for (int o = t; o < MB * CLS_F; o += 256) {
        int m = o / CLS_F, c = o % CLS_F;
        float s = b2[c];
        const float* tr = ts + m * HID_F;
        for (int j = 0; j < HID_F; j++) s = fmaf(tr[j], W2[j * CLS_F + c], s);
        out[(size_t)(n0 + m) * CLS_F + c] = s;
    }
}

// ---------------- launch ----------------

extern "C" void kernel_launch(void* const* d_in, const int* in_sizes, int n_in,
                              void* d_out, int out_size, void* d_ws, size_t ws_size,
                              hipStream_t stream) {
    const float* features = (const float*)d_in[0];
    const int*   src      = (const int*)d_in[1];
    const int*   dst      = (const int*)d_in[2];
    const float* W1       = (const float*)d_in[3];
    const float* b1       = (const float*)d_in[4];
    const float* W2       = (const float*)d_in[5];
    const float* b2       = (const float*)d_in[6];
    float*       out      = (float*)d_out;

    char* ws = (char*)d_ws;
    size_t off = 0;
    auto alloc = [&](size_t bytes) -> void* {
        void* p = ws + off;
        off += (bytes + 255) & ~(size_t)255;
        return p;
    };
    int*   counts = (int*)alloc((size_t)N_NODES * 4);
    int*   rowptr = (int*)alloc((size_t)N_NODES * 4);
    int*   cursor = (int*)alloc((size_t)N_NODES * 4);
    int*   bsum   = (int*)alloc(256 * 4);
    float* norm   = (float*)alloc((size_t)N_NODES * 4);
    float* norm2  = (float*)alloc((size_t)N_NODES * 4);
    int*   csr    = (int*)alloc((size_t)N_EDGES * 4);
    float* h1     = (float*)alloc((size_t)N_NODES * IN_F * 4);
    float* h2     = (float*)alloc((size_t)N_NODES * IN_F * 4);

    hipMemsetAsync(counts, 0, (size_t)N_NODES * 4, stream);

    int nb = (N_NODES + 255) / 256;   // 157
    k_count<<<(N_EDGES + 255) / 256, 256, 0, stream>>>(dst, counts);
    k_scan1<<<nb, 256, 0, stream>>>(counts, bsum);
    k_scan2<<<1, 64, 0, stream>>>(bsum, nb);
    k_scan3<<<nb, 256, 0, stream>>>(counts, bsum, rowptr, cursor);
    k_norm<<<nb, 256, 0, stream>>>(counts, norm, norm2);
    k_fill<<<(N_EDGES + 255) / 256, 256, 0, stream>>>(src, dst, cursor, csr);

    // hop1: scale by norm[src]; hop2: scale by norm^2[src]; trailing norm folded into MLP
    k_hop<<<(N_NODES + 7) / 8, 256, 0, stream>>>(features, h1, csr, rowptr, counts, norm);
    k_hop<<<(N_NODES + 7) / 8, 256, 0, stream>>>(h1, h2, csr, rowptr, counts, norm2);

    k_mlp<<<N_NODES / MB, 256, 0, stream>>>(h2, norm, W1, b1, W2, b2, out);
}